// Round 18
// baseline (144.824 us; speedup 1.0000x reference)
//
#include <hip/hip_runtime.h>
#include <hip/hip_bf16.h>
#include <math.h>

#define BB 4
#define CC 256
#define HH 64
#define WW 64
#define HW 4096
#define PH 68
#define PW 68
#define COUT 256
#define OFFC 216
#define KTOT 2304
#define NCHUNK 72

typedef __attribute__((ext_vector_type(4))) float f32x4;
typedef __attribute__((ext_vector_type(8))) short s16x8;
typedef __attribute__((ext_vector_type(8))) unsigned short u16x8;
typedef __attribute__((ext_vector_type(2))) unsigned int u32x2;

__device__ __forceinline__ unsigned short f2bf(float f) {
    unsigned int u = __float_as_uint(f);
    return (unsigned short)((u + 0x7fffu + ((u >> 16) & 1u)) >> 16);
}
__device__ __forceinline__ float bflo(unsigned int u) { return __uint_as_float(u << 16); }
__device__ __forceinline__ float bfhi(unsigned int u) { return __uint_as_float(u & 0xffff0000u); }
__device__ __forceinline__ unsigned int pkbf(float a, float b) {
    __hip_bfloat162 h = __float22bfloat162_rn(make_float2(a, b));
    unsigned int r;
    __builtin_memcpy(&r, &h, 4);
    return r;
}

#define WAITL() asm volatile("s_waitcnt lgkmcnt(0)" ::: "memory")
#define RBAR() __builtin_amdgcn_s_barrier()

// ---------- pack main weight, k-swizzled per oc row (2-row granular)
__global__ __launch_bounds__(256) void pack_w_main(const float* __restrict__ w,
                                                   unsigned short* __restrict__ wp) {
    int idx = blockIdx.x * 256 + threadIdx.x;
    int t = idx >> 13, r = idx & 8191;
    int oc = r >> 5, s = (r >> 3) & 3, e = r & 7;
    int kk = ((s ^ ((oc >> 1) & 3)) << 3) | e;
    int dg = t / 9, tap = t - dg * 9;
    int c = dg * 32 + kk;
    wp[idx] = f2bf(w[((size_t)oc * CC + c) * 9 + tap]);
}

// ---------- pack offset weight (pad 216->256), t = tap*8+cg, same swizzle
__global__ __launch_bounds__(256) void pack_w_off(const float* __restrict__ w,
                                                  unsigned short* __restrict__ wp) {
    int idx = blockIdx.x * 256 + threadIdx.x;
    int t = idx >> 13, r = idx & 8191;
    int oc = r >> 5, s = (r >> 3) & 3, e = r & 7;
    int kk = ((s ^ ((oc >> 1) & 3)) << 3) | e;
    int tap = t >> 3, cg = t & 7;
    int c = cg * 32 + kk;
    float v = (oc < OFFC) ? w[((size_t)oc * CC + c) * 9 + tap] : 0.f;
    wp[idx] = f2bf(v);
}

// ---------- NCHW f32 -> padded NHWC bf16 (zero ring of 2), LDS-transposed coalesced
__global__ __launch_bounds__(256) void pad_tr2(const float* __restrict__ srcx,
                                               const float* __restrict__ srce,
                                               unsigned short* __restrict__ dx_,
                                               unsigned short* __restrict__ de_) {
    const float* src = blockIdx.y ? srce : srcx;
    unsigned short* dst = blockIdx.y ? de_ : dx_;
    int blk = blockIdx.x;
    int b = blk / PH, yp = blk % PH;
    int y = yp - 2;
    unsigned short* drow = dst + ((size_t)b * PH + yp) * PW * CC;
    int tid = threadIdx.x;
    if ((unsigned)y >= (unsigned)HH) {
        for (int i = tid; i < PW * CC / 8; i += 256) *(u16x8*)&drow[(size_t)i * 8] = (u16x8)0;
        return;
    }
    __shared__ float tile[64][65];
    int lane = tid & 63, w = tid >> 6;
    int oct = tid & 7, xi = tid >> 3;
    const float* srow = src + (size_t)b * CC * HW + (size_t)y * WW;
    for (int chunk = 0; chunk < 4; chunk++) {
        __syncthreads();
#pragma unroll
        for (int i = 0; i < 16; i++) {
            int c = chunk * 64 + w * 16 + i;
            tile[w * 16 + i][lane] = srow[(size_t)c * HW + lane];
        }
        __syncthreads();
#pragma unroll
        for (int xq = 0; xq < 3; xq++) {
            int xp = xq * 32 + xi;
            if (xp < PW) {
                int x = xp - 2;
                u16x8 v = (u16x8)0;
                if ((unsigned)x < (unsigned)WW) {
#pragma unroll
                    for (int e = 0; e < 8; e++) v[e] = f2bf(tile[oct * 8 + e][x]);
                }
                *(u16x8*)&drow[(size_t)xp * CC + chunk * 64 + oct * 8] = v;
            }
        }
    }
}

// ======================================================================
// FUSED kernel (R15 base). Phase 1: barrier-free, LDS-free register GEMM —
// B fragments loaded per-lane direct from global (natural k-order matches
// the A-pack XOR cancellation). Phase 2: unchanged R15 (LDS dbuf B).
// Block 512 thr = 8 waves, M=256 x N=32, grid (256 rows, 2 px-halves).
// ======================================================================

#define A_LOAD(WPP, T, AF)                                                \
    {                                                                     \
        const unsigned short* wt_ = WPP + (size_t)(T) * 8192 + aoff;      \
        AF[0] = *(const s16x8*)&wt_[0];                                   \
        AF[1] = *(const s16x8*)&wt_[512];                                 \
        AF[2] = *(const s16x8*)&wt_[8192];                                \
        AF[3] = *(const s16x8*)&wt_[8704];                                \
    }

#define MFMA8R(AC, BUF)                                                                      \
    {                                                                                        \
        int sw_ = (lg ^ ((r16 >> 1) & 3)) << 3;                                              \
        s16x8 b0_ = *(const s16x8*)&sB[BUF][0][r16 * 32 + sw_];                              \
        s16x8 b1_ = *(const s16x8*)&sB[BUF][0][(16 + r16) * 32 + sw_];                       \
        acc[0][0] = __builtin_amdgcn_mfma_f32_16x16x32_bf16(AC[0], b0_, acc[0][0], 0, 0, 0); \
        acc[0][1] = __builtin_amdgcn_mfma_f32_16x16x32_bf16(AC[0], b1_, acc[0][1], 0, 0, 0); \
        acc[1][0] = __builtin_amdgcn_mfma_f32_16x16x32_bf16(AC[1], b0_, acc[1][0], 0, 0, 0); \
        acc[1][1] = __builtin_amdgcn_mfma_f32_16x16x32_bf16(AC[1], b1_, acc[1][1], 0, 0, 0); \
        b0_ = *(const s16x8*)&sB[BUF][1][r16 * 32 + sw_];                                    \
        b1_ = *(const s16x8*)&sB[BUF][1][(16 + r16) * 32 + sw_];                             \
        acc[0][0] = __builtin_amdgcn_mfma_f32_16x16x32_bf16(AC[2], b0_, acc[0][0], 0, 0, 0); \
        acc[0][1] = __builtin_amdgcn_mfma_f32_16x16x32_bf16(AC[2], b1_, acc[0][1], 0, 0, 0); \
        acc[1][0] = __builtin_amdgcn_mfma_f32_16x16x32_bf16(AC[3], b0_, acc[1][0], 0, 0, 0); \
        acc[1][1] = __builtin_amdgcn_mfma_f32_16x16x32_bf16(AC[3], b1_, acc[1][1], 0, 0, 0); \
    }

__global__ __launch_bounds__(512, 4) void fused_dcn(const unsigned short* __restrict__ eT,
                                                    const unsigned short* __restrict__ xT,
                                                    const unsigned short* __restrict__ wpo,
                                                    const unsigned short* __restrict__ wpm,
                                                    const float* __restrict__ off_b,
                                                    const float* __restrict__ bias,
                                                    float* __restrict__ out) {
    __shared__ __align__(16) unsigned short sB[2][2][1024];   // 8 KB (phase 2 only)
    __shared__ unsigned int sOP[NCHUNK][32][3];               // 27.65 KB

    int bx = blockIdx.x;
    int b = bx >> 6, y = bx & 63;
    int pxh = blockIdx.y;
    int tid = threadIdx.x;
    int lane = tid & 63;
    int w = tid >> 6;
    int r16 = lane & 15, lg = lane >> 4;
    int aoff = (w * 32 + r16) * 32 + ((lg ^ ((r16 >> 1) & 3)) << 3);
    // phase-2 sample thread map
    int kt = tid >> 8;
    int p2px = (tid >> 3) & 31;
    int ch4 = tid & 7;

    const unsigned short* eb = eT + (size_t)b * PH * PW * CC;
    const unsigned short* xb = xT + (size_t)b * PH * PW * CC;

    f32x4 acc[2][2];
#pragma unroll
    for (int mi = 0; mi < 2; mi++)
#pragma unroll
        for (int ni = 0; ni < 2; ni++) acc[mi][ni] = (f32x4)0.f;

    s16x8 aA[4], aB[4];

    // =================== phase 1: offset GEMM, LDS-free, barrier-free ===================
    for (int t = 0; t < NCHUNK; t += 2) {
        A_LOAD(wpo, t, aA)
        s16x8 bf[4];
#pragma unroll
        for (int kti = 0; kti < 2; kti++) {
            int tt = t + kti;
            int tap_ = tt >> 3, cg_ = tt & 7;
            int ky_ = tap_ / 3, kx_ = tap_ - ky_ * 3;
#pragma unroll
            for (int ni = 0; ni < 2; ni++) {
                int px_ = pxh * 32 + ni * 16 + r16;
                bf[kti * 2 + ni] = *(const s16x8*)&eb[(size_t)((y + ky_ + 1) * PW +
                                                               (px_ + kx_ + 1)) * CC +
                                                      cg_ * 32 + lg * 8];
            }
        }
#pragma unroll
        for (int kti = 0; kti < 2; kti++) {
#pragma unroll
            for (int ni = 0; ni < 2; ni++) {
                acc[0][ni] = __builtin_amdgcn_mfma_f32_16x16x32_bf16(aA[kti * 2], bf[kti * 2 + ni],
                                                                     acc[0][ni], 0, 0, 0);
                acc[1][ni] = __builtin_amdgcn_mfma_f32_16x16x32_bf16(aA[kti * 2 + 1],
                                                                     bf[kti * 2 + ni],
                                                                     acc[1][ni], 0, 0, 0);
            }
        }
    }

    // ============ epilogue scatter: acc+off_b -> sOP as f32 ============
    __syncthreads();
#pragma unroll
    for (int mi = 0; mi < 2; mi++) {
#pragma unroll
        for (int ni = 0; ni < 2; ni++) {
#pragma unroll
            for (int j = 0; j < 4; j++) {
                int oc = w * 32 + mi * 16 + lg * 4 + j;
                if (oc < OFFC) {
                    int dg, tap, comp;
                    if (oc < 144) {
                        dg = oc / 18;
                        int rr = oc - dg * 18;
                        tap = rr >> 1;
                        comp = rr & 1;
                    } else {
                        int o2 = oc - 144;
                        dg = o2 / 9;
                        tap = o2 - dg * 9;
                        comp = 2;
                    }
                    sOP[dg * 9 + tap][ni * 16 + r16][comp] =
                        __float_as_uint(acc[mi][ni][j] + off_b[oc]);
                }
            }
        }
    }
    __syncthreads();
    // ============ prep: in-place convert {dy,dx,mr} -> {idx,w01,w23} ============
    for (int i = tid; i < NCHUNK * 32; i += 512) {
        int tt = i >> 5, px = i & 31;
        int dg = (tt * 57) >> 9;
        int tap = tt - dg * 9;
        int ky = tap / 3, kx = tap - ky * 3;
        float dyv = __uint_as_float(sOP[tt][px][0]);
        float dxv = __uint_as_float(sOP[tt][px][1]);
        float mr = __uint_as_float(sOP[tt][px][2]);
        int xg = pxh * 32 + px;
        float mv = 1.f / (1.f + __expf(-mr));
        float py = (float)(y + ky - 1) + dyv;
        float pxx = (float)(xg + kx - 1) + dxv;
        float y0f = floorf(py), x0f = floorf(pxx);
        float fy = py - y0f, fx = pxx - x0f;
        int yp0 = min(max((int)y0f + 2, 0), PH - 1);
        int yp1 = min(max((int)y0f + 3, 0), PH - 1);
        int xp0 = min(max((int)x0f + 2, 0), PW - 1);
        int xp1 = min(max((int)x0f + 3, 0), PW - 1);
        float w00 = (1.f - fy) * (1.f - fx) * mv;
        float w01 = (1.f - fy) * fx * mv;
        float w10 = fy * (1.f - fx) * mv;
        float w11 = fy * fx * mv;
        sOP[tt][px][0] = (unsigned int)(yp0 * PW + xp0) | ((unsigned int)(xp1 - xp0) << 13) |
                         ((unsigned int)(yp1 - yp0) << 14);
        sOP[tt][px][1] = pkbf(w00, w01);
        sOP[tt][px][2] = pkbf(w10, w11);
    }
    __syncthreads();

    // =================== phase 2: main GEMM + sampling (R15, unchanged) ===================
#pragma unroll
    for (int mi = 0; mi < 2; mi++)
#pragma unroll
        for (int ni = 0; ni < 2; ni++) acc[mi][ni] = (f32x4)0.f;

#define BSLOT4 (p2px * 32 + ((((ch4 >> 1) ^ ((p2px >> 1) & 3))) << 3) + (ch4 & 1) * 4)
#define DC_G(T, G00, G01, G10, G11)                                       \
    {                                                                     \
        int dg_ = ((T) * 57) >> 9;                                        \
        unsigned int iv_ = sOP[T][p2px][0];                               \
        int o00_ = (int)(iv_ & 8191u) << 8;                               \
        int dxe_ = (int)((iv_ >> 13) & 1u) << 8;                          \
        int dye_ = ((iv_ >> 14) & 1u) ? (PW * CC) : 0;                    \
        const unsigned short* p_ = xb + dg_ * 32 + ch4 * 4;               \
        G00 = *(const u32x2*)(p_ + o00_);                                 \
        G01 = *(const u32x2*)(p_ + o00_ + dxe_);                          \
        G10 = *(const u32x2*)(p_ + o00_ + dye_);                          \
        G11 = *(const u32x2*)(p_ + o00_ + dye_ + dxe_);                   \
    }
#define DC_FIN(T, G00, G01, G10, G11, BUF)                                                \
    {                                                                                     \
        unsigned int wa_ = sOP[T][p2px][1];                                               \
        unsigned int wb_ = sOP[T][p2px][2];                                               \
        float w00 = bflo(wa_), w01 = bfhi(wa_);                                           \
        float w10 = bflo(wb_), w11 = bfhi(wb_);                                           \
        float v0 = w00 * bflo(G00[0]) + w01 * bflo(G01[0]) + w10 * bflo(G10[0]) +         \
                   w11 * bflo(G11[0]);                                                    \
        float v1 = w00 * bfhi(G00[0]) + w01 * bfhi(G01[0]) + w10 * bfhi(G10[0]) +         \
                   w11 * bfhi(G11[0]);                                                    \
        float v2 = w00 * bflo(G00[1]) + w01 * bflo(G01[1]) + w10 * bflo(G10[1]) +         \
                   w11 * bflo(G11[1]);                                                    \
        float v3 = w00 * bfhi(G00[1]) + w01 * bfhi(G01[1]) + w10 * bfhi(G10[1]) +         \
                   w11 * bfhi(G11[1]);                                                    \
        u32x2 pk_;                                                                        \
        pk_[0] = pkbf(v0, v1);                                                            \
        pk_[1] = pkbf(v2, v3);                                                            \
        *(u32x2*)&sB[BUF][kt][BSLOT4] = pk_;                                              \
    }
#define DC_ITF(T, BUF, AC, AN, GP0, GP1, GP2, GP3, GN0, GN1, GN2, GN3)     \
    {                                                                      \
        A_LOAD(wpm, (T) + 2, AN)                                           \
        DC_G((T) + 4 + kt, GN0, GN1, GN2, GN3)                             \
        MFMA8R(AC, BUF)                                                    \
        DC_FIN((T) + 2 + kt, GP0, GP1, GP2, GP3, (BUF) ^ 1)                \
        WAITL();                                                           \
        RBAR();                                                            \
    }

    {
        u32x2 gA0, gA1, gA2, gA3, gB0, gB1, gB2, gB3;
        {  // prologue
            A_LOAD(wpm, 0, aA)
            u32x2 t0, t1, t2, t3;
            DC_G(kt, t0, t1, t2, t3)
            DC_FIN(kt, t0, t1, t2, t3, 0)
            DC_G(2 + kt, gA0, gA1, gA2, gA3)
            WAITL();
            RBAR();
        }
        for (int t = 0; t < 64; t += 4) {
            DC_ITF(t, 0, aA, aB, gA0, gA1, gA2, gA3, gB0, gB1, gB2, gB3)
            DC_ITF(t + 2, 1, aB, aA, gB0, gB1, gB2, gB3, gA0, gA1, gA2, gA3)
        }
        DC_ITF(64, 0, aA, aB, gA0, gA1, gA2, gA3, gB0, gB1, gB2, gB3)
        DC_ITF(66, 1, aB, aA, gB0, gB1, gB2, gB3, gA0, gA1, gA2, gA3)
        {  // T=68: no more gathers to issue
            A_LOAD(wpm, 70, aB)
            MFMA8R(aA, 0)
            DC_FIN(70 + kt, gA0, gA1, gA2, gA3, 1)
            WAITL();
            RBAR();
        }
        MFMA8R(aB, 1)  // T=70
    }

#pragma unroll
    for (int mi = 0; mi < 2; mi++) {
#pragma unroll
        for (int ni = 0; ni < 2; ni++) {
#pragma unroll
            for (int j = 0; j < 4; j++) {
                int oc = w * 32 + mi * 16 + lg * 4 + j;
                int pxo = pxh * 32 + ni * 16 + r16;
                out[(size_t)(b * COUT + oc) * HW + y * WW + pxo] = acc[mi][ni][j] + bias[oc];
            }
        }
    }
}

extern "C" void kernel_launch(void* const* d_in, const int* in_sizes, int n_in,
                              void* d_out, int out_size, void* d_ws, size_t ws_size,
                              hipStream_t stream) {
    const float* x = (const float*)d_in[0];
    const float* extra_feat = (const float*)d_in[1];
    const float* weight = (const float*)d_in[2];
    const float* bias = (const float*)d_in[3];
    const float* off_w = (const float*)d_in[4];
    const float* off_b = (const float*)d_in[5];
    float* out = (float*)d_out;

    unsigned short* wpm = (unsigned short*)d_ws;            // 1.18 MB
    unsigned short* wpo = wpm + (size_t)KTOT * COUT;        // 1.18 MB
    unsigned short* xT = wpo + (size_t)KTOT * COUT;         // 9.05 MB
    unsigned short* eT = xT + (size_t)BB * PH * PW * CC;    // 9.05 MB

    pack_w_main<<<(KTOT * COUT) / 256, 256, 0, stream>>>(weight, wpm);
    pack_w_off<<<(KTOT * COUT) / 256, 256, 0, stream>>>(off_w, wpo);
    pad_tr2<<<dim3(BB * PH, 2), 256, 0, stream>>>(x, extra_feat, xT, eT);

    fused_dcn<<<dim3(BB * HH, 2), 512, 0, stream>>>(eT, xT, wpo, wpm, off_b, bias, out);
}

// Round 19
// 136.967 us; speedup vs baseline: 1.0574x; 1.0574x over previous
//
#include <hip/hip_runtime.h>
#include <hip/hip_bf16.h>
#include <math.h>

#define BB 4
#define CC 256
#define HH 64
#define WW 64
#define HW 4096
#define PH 68
#define PW 68
#define COUT 256
#define OFFC 216
#define KTOT 2304
#define NCHUNK 72

typedef __attribute__((ext_vector_type(4))) float f32x4;
typedef __attribute__((ext_vector_type(8))) short s16x8;
typedef __attribute__((ext_vector_type(8))) unsigned short u16x8;

__device__ __forceinline__ unsigned short f2bf(float f) {
    unsigned int u = __float_as_uint(f);
    return (unsigned short)((u + 0x7fffu + ((u >> 16) & 1u)) >> 16);
}
__device__ __forceinline__ float bflo(unsigned int u) { return __uint_as_float(u << 16); }
__device__ __forceinline__ float bfhi(unsigned int u) { return __uint_as_float(u & 0xffff0000u); }
__device__ __forceinline__ unsigned int pkbf(float a, float b) {
    __hip_bfloat162 h = __float22bfloat162_rn(make_float2(a, b));
    unsigned int r;
    __builtin_memcpy(&r, &h, 4);
    return r;
}

#define WAITL() asm volatile("s_waitcnt lgkmcnt(0)" ::: "memory")
#define RBAR() __builtin_amdgcn_s_barrier()

// ---------- pack main weight, k-swizzled per oc row (2-row granular)
__global__ __launch_bounds__(256) void pack_w_main(const float* __restrict__ w,
                                                   unsigned short* __restrict__ wp) {
    int idx = blockIdx.x * 256 + threadIdx.x;
    int t = idx >> 13, r = idx & 8191;
    int oc = r >> 5, s = (r >> 3) & 3, e = r & 7;
    int kk = ((s ^ ((oc >> 1) & 3)) << 3) | e;
    int dg = t / 9, tap = t - dg * 9;
    int c = dg * 32 + kk;
    wp[idx] = f2bf(w[((size_t)oc * CC + c) * 9 + tap]);
}

// ---------- pack offset weight (pad 216->256), t = tap*8+cg, same swizzle
__global__ __launch_bounds__(256) void pack_w_off(const float* __restrict__ w,
                                                  unsigned short* __restrict__ wp) {
    int idx = blockIdx.x * 256 + threadIdx.x;
    int t = idx >> 13, r = idx & 8191;
    int oc = r >> 5, s = (r >> 3) & 3, e = r & 7;
    int kk = ((s ^ ((oc >> 1) & 3)) << 3) | e;
    int tap = t >> 3, cg = t & 7;
    int c = cg * 32 + kk;
    float v = (oc < OFFC) ? w[((size_t)oc * CC + c) * 9 + tap] : 0.f;
    wp[idx] = f2bf(v);
}

// ---------- NCHW f32 -> padded NHWC bf16 (zero ring of 2), LDS-transposed coalesced
__global__ __launch_bounds__(256) void pad_tr2(const float* __restrict__ srcx,
                                               const float* __restrict__ srce,
                                               unsigned short* __restrict__ dx_,
                                               unsigned short* __restrict__ de_) {
    const float* src = blockIdx.y ? srce : srcx;
    unsigned short* dst = blockIdx.y ? de_ : dx_;
    int blk = blockIdx.x;
    int b = blk / PH, yp = blk % PH;
    int y = yp - 2;
    unsigned short* drow = dst + ((size_t)b * PH + yp) * PW * CC;
    int tid = threadIdx.x;
    if ((unsigned)y >= (unsigned)HH) {
        for (int i = tid; i < PW * CC / 8; i += 256) *(u16x8*)&drow[(size_t)i * 8] = (u16x8)0;
        return;
    }
    __shared__ float tile[64][65];
    int lane = tid & 63, w = tid >> 6;
    int oct = tid & 7, xi = tid >> 3;
    const float* srow = src + (size_t)b * CC * HW + (size_t)y * WW;
    for (int chunk = 0; chunk < 4; chunk++) {
        __syncthreads();
#pragma unroll
        for (int i = 0; i < 16; i++) {
            int c = chunk * 64 + w * 16 + i;
            tile[w * 16 + i][lane] = srow[(size_t)c * HW + lane];
        }
        __syncthreads();
#pragma unroll
        for (int xq = 0; xq < 3; xq++) {
            int xp = xq * 32 + xi;
            if (xp < PW) {
                int x = xp - 2;
                u16x8 v = (u16x8)0;
                if ((unsigned)x < (unsigned)WW) {
#pragma unroll
                    for (int e = 0; e < 8; e++) v[e] = f2bf(tile[oct * 8 + e][x]);
                }
                *(u16x8*)&drow[(size_t)xp * CC + chunk * 64 + oct * 8] = v;
            }
        }
    }
}

// ======================================================================
// FUSED kernel, 1024 threads = 16 waves (wave tile 32oc x 16px).
// Identical structure to R16 but with a RELAXED launch bound: the
// allocator takes its natural ~55-64 VGPR (no starvation, no spills);
// at <=64 VGPR the HW co-schedules 2 blocks/CU -> 32 waves/CU.
// ======================================================================

#define A_LOAD(WPP, T, AF)                                                \
    {                                                                     \
        const unsigned short* wt_ = WPP + (size_t)(T) * 8192 + aoff;      \
        AF[0] = *(const s16x8*)&wt_[0];                                   \
        AF[1] = *(const s16x8*)&wt_[512];                                 \
        AF[2] = *(const s16x8*)&wt_[8192];                                \
        AF[3] = *(const s16x8*)&wt_[8704];                                \
    }

// 4 MFMA: wave tile 32oc x 16px, K=64
#define MFMA4R(AC, BUF)                                                                      \
    {                                                                                        \
        int sw_ = (lg ^ ((r16 >> 1) & 3)) << 3;                                              \
        s16x8 b0_ = *(const s16x8*)&sB[BUF][0][(wn * 16 + r16) * 32 + sw_];                  \
        acc[0] = __builtin_amdgcn_mfma_f32_16x16x32_bf16(AC[0], b0_, acc[0], 0, 0, 0);       \
        acc[1] = __builtin_amdgcn_mfma_f32_16x16x32_bf16(AC[1], b0_, acc[1], 0, 0, 0);       \
        b0_ = *(const s16x8*)&sB[BUF][1][(wn * 16 + r16) * 32 + sw_];                        \
        acc[0] = __builtin_amdgcn_mfma_f32_16x16x32_bf16(AC[2], b0_, acc[0], 0, 0, 0);       \
        acc[1] = __builtin_amdgcn_mfma_f32_16x16x32_bf16(AC[3], b0_, acc[1], 0, 0, 0);       \
    }

__global__ __launch_bounds__(1024) void fused_dcn(const unsigned short* __restrict__ eT,
                                                  const unsigned short* __restrict__ xT,
                                                  const unsigned short* __restrict__ wpo,
                                                  const unsigned short* __restrict__ wpm,
                                                  const float* __restrict__ off_b,
                                                  const float* __restrict__ bias,
                                                  float* __restrict__ out) {
    __shared__ __align__(16) unsigned short sB[2][2][1024];   // 8 KB
    __shared__ unsigned int sOP[NCHUNK][32][3];               // 27.65 KB (f32 then u32 in place)

    int bx = blockIdx.x;
    int b = bx >> 6, y = bx & 63;
    int pxh = blockIdx.y;
    int tid = threadIdx.x;
    int lane = tid & 63;
    int w = tid >> 6;              // 0..15
    int wm = w & 7, wn = w >> 3;   // 8 M-slices x 2 N-halves
    int r16 = lane & 15, lg = lane >> 4;
    int aoff = (wm * 32 + r16) * 32 + ((lg ^ ((r16 >> 1) & 3)) << 3);
    // staging thread map (both phases): one K32-chunk per thread
    int ktc = tid >> 9;            // 0/1: which chunk of the pair
    int spx = (tid >> 4) & 31;     // pixel 0..31
    int ch2 = tid & 15;            // 2-channel group
    int pxg = pxh * 32 + spx;

    const unsigned short* eb = eT + (size_t)b * PH * PW * CC;
    const unsigned short* xb = xT + (size_t)b * PH * PW * CC;

    f32x4 acc[2];
    acc[0] = (f32x4)0.f;
    acc[1] = (f32x4)0.f;

    s16x8 aA[4], aB[4];

#define BSLOT (spx * 32 + (((ch2 >> 2) ^ ((spx >> 1) & 3)) << 3) + (ch2 & 3) * 2)

    // =================== phase 1: offset GEMM ===================
#define OF_B(T, BV)                                                                          \
    {                                                                                        \
        int tap_ = (T) >> 3, cg_ = (T) & 7;                                                  \
        int ky_ = tap_ / 3, kx_ = tap_ - ky_ * 3;                                            \
        BV = *(const unsigned int*)&eb[(size_t)((y + ky_ + 1) * PW + (pxg + kx_ + 1)) * CC + \
                                       cg_ * 32 + ch2 * 2];                                  \
    }
#define OF_ITF(T, BUF, AC, AN, BP, BN)                           \
    {                                                            \
        A_LOAD(wpo, (T) + 2, AN)                                 \
        OF_B((T) + 4 + ktc, BN)                                  \
        MFMA4R(AC, BUF)                                          \
        *(unsigned int*)&sB[(BUF) ^ 1][ktc][BSLOT] = BP;         \
        WAITL();                                                 \
        RBAR();                                                  \
    }

    {
        unsigned int bP, bN;
        {  // prologue
            A_LOAD(wpo, 0, aA)
            unsigned int c0;
            OF_B(ktc, c0)
            *(unsigned int*)&sB[0][ktc][BSLOT] = c0;
            OF_B(2 + ktc, bP)
            WAITL();
            RBAR();
        }
        for (int t = 0; t < 68; t += 4) {
            OF_ITF(t, 0, aA, aB, bP, bN)
            OF_ITF(t + 2, 1, aB, aA, bN, bP)
        }
        {  // T=68 tail: write last pair (70,71)
            A_LOAD(wpo, 70, aB)
            MFMA4R(aA, 0)
            *(unsigned int*)&sB[1][ktc][BSLOT] = bP;
            WAITL();
            RBAR();
        }
        MFMA4R(aB, 1)  // T=70
    }

    // ============ epilogue scatter: acc+off_b -> sOP as f32 ============
    __syncthreads();
#pragma unroll
    for (int mi = 0; mi < 2; mi++) {
#pragma unroll
        for (int j = 0; j < 4; j++) {
            int oc = wm * 32 + mi * 16 + lg * 4 + j;
            if (oc < OFFC) {
                int dg, tap, comp;
                if (oc < 144) {
                    dg = oc / 18;
                    int rr = oc - dg * 18;
                    tap = rr >> 1;
                    comp = rr & 1;
                } else {
                    int o2 = oc - 144;
                    dg = o2 / 9;
                    tap = o2 - dg * 9;
                    comp = 2;
                }
                sOP[dg * 9 + tap][wn * 16 + r16][comp] =
                    __float_as_uint(acc[mi][j] + off_b[oc]);
            }
        }
    }
    __syncthreads();
    // ============ prep: in-place convert {dy,dx,mr} -> {idx,w01,w23} ============
    for (int i = tid; i < NCHUNK * 32; i += 1024) {
        int tt = i >> 5, px = i & 31;
        int dg = (tt * 57) >> 9;
        int tap = tt - dg * 9;
        int ky = tap / 3, kx = tap - ky * 3;
        float dyv = __uint_as_float(sOP[tt][px][0]);
        float dxv = __uint_as_float(sOP[tt][px][1]);
        float mr = __uint_as_float(sOP[tt][px][2]);
        int xg = pxh * 32 + px;
        float mv = 1.f / (1.f + __expf(-mr));
        float py = (float)(y + ky - 1) + dyv;
        float pxx = (float)(xg + kx - 1) + dxv;
        float y0f = floorf(py), x0f = floorf(pxx);
        float fy = py - y0f, fx = pxx - x0f;
        int yp0 = min(max((int)y0f + 2, 0), PH - 1);
        int yp1 = min(max((int)y0f + 3, 0), PH - 1);
        int xp0 = min(max((int)x0f + 2, 0), PW - 1);
        int xp1 = min(max((int)x0f + 3, 0), PW - 1);
        float w00 = (1.f - fy) * (1.f - fx) * mv;
        float w01 = (1.f - fy) * fx * mv;
        float w10 = fy * (1.f - fx) * mv;
        float w11 = fy * fx * mv;
        sOP[tt][px][0] = (unsigned int)(yp0 * PW + xp0) | ((unsigned int)(xp1 - xp0) << 13) |
                         ((unsigned int)(yp1 - yp0) << 14);
        sOP[tt][px][1] = pkbf(w00, w01);
        sOP[tt][px][2] = pkbf(w10, w11);
    }
    __syncthreads();

    // =================== phase 2: main GEMM + sampling ===================
    acc[0] = (f32x4)0.f;
    acc[1] = (f32x4)0.f;

#define DC_G(T, G00, G01, G10, G11)                                       \
    {                                                                     \
        int dg_ = ((T) * 57) >> 9;                                        \
        unsigned int iv_ = sOP[T][spx][0];                                \
        int o00_ = (int)(iv_ & 8191u) << 8;                               \
        int dxe_ = (int)((iv_ >> 13) & 1u) << 8;                          \
        int dye_ = ((iv_ >> 14) & 1u) ? (PW * CC) : 0;                    \
        const unsigned short* p_ = xb + dg_ * 32 + ch2 * 2;               \
        G00 = *(const unsigned int*)(p_ + o00_);                          \
        G01 = *(const unsigned int*)(p_ + o00_ + dxe_);                   \
        G10 = *(const unsigned int*)(p_ + o00_ + dye_);                   \
        G11 = *(const unsigned int*)(p_ + o00_ + dye_ + dxe_);            \
    }
#define DC_FIN(T, G00, G01, G10, G11, BUF)                                                \
    {                                                                                     \
        unsigned int wa_ = sOP[T][spx][1];                                                \
        unsigned int wb_ = sOP[T][spx][2];                                                \
        float w00 = bflo(wa_), w01 = bfhi(wa_);                                           \
        float w10 = bflo(wb_), w11 = bfhi(wb_);                                           \
        float v0 = w00 * bflo(G00) + w01 * bflo(G01) + w10 * bflo(G10) + w11 * bflo(G11); \
        float v1 = w00 * bfhi(G00) + w01 * bfhi(G01) + w10 * bfhi(G10) + w11 * bfhi(G11); \
        *(unsigned int*)&sB[BUF][ktc][BSLOT] = pkbf(v0, v1);                              \
    }
#define DC_ITF(T, BUF, AC, AN, GP0, GP1, GP2, GP3, GN0, GN1, GN2, GN3)     \
    {                                                                      \
        A_LOAD(wpm, (T) + 2, AN)                                           \
        DC_G((T) + 4 + ktc, GN0, GN1, GN2, GN3)                            \
        MFMA4R(AC, BUF)                                                    \
        DC_FIN((T) + 2 + ktc, GP0, GP1, GP2, GP3, (BUF) ^ 1)               \
        WAITL();                                                           \
        RBAR();                                                            \
    }

    {
        unsigned int gA0, gA1, gA2, gA3, gB0, gB1, gB2, gB3;
        {  // prologue
            A_LOAD(wpm, 0, aA)
            unsigned int t0, t1, t2, t3;
            DC_G(ktc, t0, t1, t2, t3)
            DC_FIN(ktc, t0, t1, t2, t3, 0)
            DC_G(2 + ktc, gA0, gA1, gA2, gA3)
            WAITL();
            RBAR();
        }
        for (int t = 0; t < 64; t += 4) {
            DC_ITF(t, 0, aA, aB, gA0, gA1, gA2, gA3, gB0, gB1, gB2, gB3)
            DC_ITF(t + 2, 1, aB, aA, gB0, gB1, gB2, gB3, gA0, gA1, gA2, gA3)
        }
        DC_ITF(64, 0, aA, aB, gA0, gA1, gA2, gA3, gB0, gB1, gB2, gB3)
        DC_ITF(66, 1, aB, aA, gB0, gB1, gB2, gB3, gA0, gA1, gA2, gA3)
        {  // T=68: no more gathers to issue
            A_LOAD(wpm, 70, aB)
            MFMA4R(aA, 0)
            DC_FIN(70 + ktc, gA0, gA1, gA2, gA3, 1)
            WAITL();
            RBAR();
        }
        MFMA4R(aB, 1)  // T=70
    }

#pragma unroll
    for (int mi = 0; mi < 2; mi++) {
#pragma unroll
        for (int j = 0; j < 4; j++) {
            int oc = wm * 32 + mi * 16 + lg * 4 + j;
            int pxo = pxh * 32 + wn * 16 + r16;
            out[(size_t)(b * COUT + oc) * HW + y * WW + pxo] = acc[mi][j] + bias[oc];
        }
    }
}

extern "C" void kernel_launch(void* const* d_in, const int* in_sizes, int n_in,
                              void* d_out, int out_size, void* d_ws, size_t ws_size,
                              hipStream_t stream) {
    const float* x = (const float*)d_in[0];
    const float* extra_feat = (const float*)d_in[1];
    const float* weight = (const float*)d_in[2];
    const float* bias = (const float*)d_in[3];
    const float* off_w = (const float*)d_in[4];
    const float* off_b = (const float*)d_in[5];
    float* out = (float*)d_out;

    unsigned short* wpm = (unsigned short*)d_ws;            // 1.18 MB
    unsigned short* wpo = wpm + (size_t)KTOT * COUT;        // 1.18 MB
    unsigned short* xT = wpo + (size_t)KTOT * COUT;         // 9.05 MB
    unsigned short* eT = xT + (size_t)BB * PH * PW * CC;    // 9.05 MB

    pack_w_main<<<(KTOT * COUT) / 256, 256, 0, stream>>>(weight, wpm);
    pack_w_off<<<(KTOT * COUT) / 256, 256, 0, stream>>>(off_w, wpo);
    pad_tr2<<<dim3(BB * PH, 2), 256, 0, stream>>>(x, extra_feat, xT, eT);

    fused_dcn<<<dim3(BB * HH, 2), 1024, 0, stream>>>(eT, xT, wpo, wpm, off_b, bias, out);
}

// Round 20
// 88.295 us; speedup vs baseline: 1.6402x; 1.5512x over previous
//
#include <hip/hip_runtime.h>
#include <hip/hip_bf16.h>
#include <math.h>

#define BB 4
#define CC 256
#define HH 64
#define WW 64
#define HW 4096
#define PH 68
#define PW 68
#define COUT 256
#define OFFC 216
#define KTOT 2304
#define NCHUNK 72

typedef __attribute__((ext_vector_type(4))) float f32x4;
typedef __attribute__((ext_vector_type(8))) short s16x8;
typedef __attribute__((ext_vector_type(8))) unsigned short u16x8;
typedef __attribute__((ext_vector_type(2))) unsigned int u32x2;

__device__ __forceinline__ unsigned short f2bf(float f) {
    unsigned int u = __float_as_uint(f);
    return (unsigned short)((u + 0x7fffu + ((u >> 16) & 1u)) >> 16);
}
__device__ __forceinline__ float bflo(unsigned int u) { return __uint_as_float(u << 16); }
__device__ __forceinline__ float bfhi(unsigned int u) { return __uint_as_float(u & 0xffff0000u); }
__device__ __forceinline__ unsigned int pkbf(float a, float b) {
    __hip_bfloat162 h = __float22bfloat162_rn(make_float2(a, b));
    unsigned int r;
    __builtin_memcpy(&r, &h, 4);
    return r;
}

#define WAITL() asm volatile("s_waitcnt lgkmcnt(0)" ::: "memory")
#define RBAR() __builtin_amdgcn_s_barrier()

// ---------- pack main weight, k-swizzled per oc row (2-row granular)
__global__ __launch_bounds__(256) void pack_w_main(const float* __restrict__ w,
                                                   unsigned short* __restrict__ wp) {
    int idx = blockIdx.x * 256 + threadIdx.x;
    int t = idx >> 13, r = idx & 8191;
    int oc = r >> 5, s = (r >> 3) & 3, e = r & 7;
    int kk = ((s ^ ((oc >> 1) & 3)) << 3) | e;
    int dg = t / 9, tap = t - dg * 9;
    int c = dg * 32 + kk;
    wp[idx] = f2bf(w[((size_t)oc * CC + c) * 9 + tap]);
}

// ---------- pack offset weight (pad 216->256), t = tap*8+cg, same swizzle
__global__ __launch_bounds__(256) void pack_w_off(const float* __restrict__ w,
                                                  unsigned short* __restrict__ wp) {
    int idx = blockIdx.x * 256 + threadIdx.x;
    int t = idx >> 13, r = idx & 8191;
    int oc = r >> 5, s = (r >> 3) & 3, e = r & 7;
    int kk = ((s ^ ((oc >> 1) & 3)) << 3) | e;
    int tap = t >> 3, cg = t & 7;
    int c = cg * 32 + kk;
    float v = (oc < OFFC) ? w[((size_t)oc * CC + c) * 9 + tap] : 0.f;
    wp[idx] = f2bf(v);
}

// ---------- NCHW f32 -> padded NHWC bf16 (zero ring of 2), LDS-transposed coalesced
__global__ __launch_bounds__(256) void pad_tr2(const float* __restrict__ srcx,
                                               const float* __restrict__ srce,
                                               unsigned short* __restrict__ dx_,
                                               unsigned short* __restrict__ de_) {
    const float* src = blockIdx.y ? srce : srcx;
    unsigned short* dst = blockIdx.y ? de_ : dx_;
    int blk = blockIdx.x;
    int b = blk / PH, yp = blk % PH;
    int y = yp - 2;
    unsigned short* drow = dst + ((size_t)b * PH + yp) * PW * CC;
    int tid = threadIdx.x;
    if ((unsigned)y >= (unsigned)HH) {
        for (int i = tid; i < PW * CC / 8; i += 256) *(u16x8*)&drow[(size_t)i * 8] = (u16x8)0;
        return;
    }
    __shared__ float tile[64][65];
    int lane = tid & 63, w = tid >> 6;
    int oct = tid & 7, xi = tid >> 3;
    const float* srow = src + (size_t)b * CC * HW + (size_t)y * WW;
    for (int chunk = 0; chunk < 4; chunk++) {
        __syncthreads();
#pragma unroll
        for (int i = 0; i < 16; i++) {
            int c = chunk * 64 + w * 16 + i;
            tile[w * 16 + i][lane] = srow[(size_t)c * HW + lane];
        }
        __syncthreads();
#pragma unroll
        for (int xq = 0; xq < 3; xq++) {
            int xp = xq * 32 + xi;
            if (xp < PW) {
                int x = xp - 2;
                u16x8 v = (u16x8)0;
                if ((unsigned)x < (unsigned)WW) {
#pragma unroll
                    for (int e = 0; e < 8; e++) v[e] = f2bf(tile[oct * 8 + e][x]);
                }
                *(u16x8*)&drow[(size_t)xp * CC + chunk * 64 + oct * 8] = v;
            }
        }
    }
}

// ======================================================================
// FUSED kernel — R13 structure verbatim (best measured: 79.5 us) plus
// XCD-aware block swizzle: each XCD owns 32 consecutive rows of one batch
// so its gathers/windows become L2-resident (grid.x 256 % 8 == 0, bijective).
// ======================================================================

#define A_LOAD(WPP, T, AF)                                                \
    {                                                                     \
        const unsigned short* wt_ = WPP + (size_t)(T) * 8192 + aoff;      \
        AF[0] = *(const s16x8*)&wt_[0];                                   \
        AF[1] = *(const s16x8*)&wt_[512];                                 \
        AF[2] = *(const s16x8*)&wt_[8192];                                \
        AF[3] = *(const s16x8*)&wt_[8704];                                \
    }

#define MFMA8R(AC, BUF)                                                                      \
    {                                                                                        \
        int sw_ = (lg ^ ((r16 >> 1) & 3)) << 3;                                              \
        s16x8 b0_ = *(const s16x8*)&sB[BUF][0][r16 * 32 + sw_];                              \
        s16x8 b1_ = *(const s16x8*)&sB[BUF][0][(16 + r16) * 32 + sw_];                       \
        acc[0][0] = __builtin_amdgcn_mfma_f32_16x16x32_bf16(AC[0], b0_, acc[0][0], 0, 0, 0); \
        acc[0][1] = __builtin_amdgcn_mfma_f32_16x16x32_bf16(AC[0], b1_, acc[0][1], 0, 0, 0); \
        acc[1][0] = __builtin_amdgcn_mfma_f32_16x16x32_bf16(AC[1], b0_, acc[1][0], 0, 0, 0); \
        acc[1][1] = __builtin_amdgcn_mfma_f32_16x16x32_bf16(AC[1], b1_, acc[1][1], 0, 0, 0); \
        b0_ = *(const s16x8*)&sB[BUF][1][r16 * 32 + sw_];                                    \
        b1_ = *(const s16x8*)&sB[BUF][1][(16 + r16) * 32 + sw_];                             \
        acc[0][0] = __builtin_amdgcn_mfma_f32_16x16x32_bf16(AC[2], b0_, acc[0][0], 0, 0, 0); \
        acc[0][1] = __builtin_amdgcn_mfma_f32_16x16x32_bf16(AC[2], b1_, acc[0][1], 0, 0, 0); \
        acc[1][0] = __builtin_amdgcn_mfma_f32_16x16x32_bf16(AC[3], b0_, acc[1][0], 0, 0, 0); \
        acc[1][1] = __builtin_amdgcn_mfma_f32_16x16x32_bf16(AC[3], b1_, acc[1][1], 0, 0, 0); \
    }

__global__ __launch_bounds__(512, 4) void fused_dcn(const unsigned short* __restrict__ eT,
                                                    const unsigned short* __restrict__ xT,
                                                    const unsigned short* __restrict__ wpo,
                                                    const unsigned short* __restrict__ wpm,
                                                    const float* __restrict__ off_b,
                                                    const float* __restrict__ bias,
                                                    float* __restrict__ out) {
    __shared__ __align__(16) unsigned short sB[2][2][1024];     // 8 KB
    __shared__ __align__(16) unsigned int prep[NCHUNK][32][3];  // 27 KB
    __shared__ float sAcc[OFFC * 33];                           // 28.5 KB

    // XCD-aware bijective swizzle: xcd = bx%8 owns rows [xcd*32, xcd*32+32)
    int bxl = (blockIdx.x & 7) * 32 + (blockIdx.x >> 3);
    int b = bxl >> 6, y = bxl & 63;
    int pxh = blockIdx.y;
    int tid = threadIdx.x;
    int lane = tid & 63;
    int w = tid >> 6;
    int r16 = lane & 15, lg = lane >> 4;
    int aoff = (w * 32 + r16) * 32 + ((lg ^ ((r16 >> 1) & 3)) << 3);
    // phase-1 B-stage thread map
    int p1px = tid >> 4, ch2 = tid & 15;
    int pxg = pxh * 32 + p1px;
    // phase-2 sample thread map
    int kt = tid >> 8;
    int p2px = (tid >> 3) & 31;
    int ch4 = tid & 7;

    const unsigned short* eb = eT + (size_t)b * PH * PW * CC;
    const unsigned short* xb = xT + (size_t)b * PH * PW * CC;

    f32x4 acc[2][2];
#pragma unroll
    for (int mi = 0; mi < 2; mi++)
#pragma unroll
        for (int ni = 0; ni < 2; ni++) acc[mi][ni] = (f32x4)0.f;

    s16x8 aA[4], aB[4];

    // =================== phase 1: offset GEMM ===================
#define BSLOT2 (p1px * 32 + ((((ch2 >> 2) ^ ((p1px >> 1) & 3))) << 3) + (ch2 & 3) * 2)
#define OF_B(T, BV)                                                                          \
    {                                                                                        \
        int tap_ = (T) >> 3, cg_ = (T) & 7;                                                  \
        int ky_ = tap_ / 3, kx_ = tap_ - ky_ * 3;                                            \
        BV = *(const unsigned int*)&eb[(size_t)((y + ky_ + 1) * PW + (pxg + kx_ + 1)) * CC + \
                                       cg_ * 32 + ch2 * 2];                                  \
    }
#define OF_ITF(T, BUF, AC, AN, BP0, BP1, BN0, BN1)               \
    {                                                            \
        A_LOAD(wpo, (T) + 2, AN)                                 \
        OF_B((T) + 4, BN0)                                       \
        OF_B((T) + 5, BN1)                                       \
        MFMA8R(AC, BUF)                                          \
        *(unsigned int*)&sB[(BUF) ^ 1][0][BSLOT2] = BP0;         \
        *(unsigned int*)&sB[(BUF) ^ 1][1][BSLOT2] = BP1;         \
        WAITL();                                                 \
        RBAR();                                                  \
    }

    {
        unsigned int bP0, bP1, bN0, bN1;
        {  // prologue
            A_LOAD(wpo, 0, aA)
            unsigned int c0, c1;
            OF_B(0, c0)
            OF_B(1, c1)
            *(unsigned int*)&sB[0][0][BSLOT2] = c0;
            *(unsigned int*)&sB[0][1][BSLOT2] = c1;
            OF_B(2, bP0)
            OF_B(3, bP1)
            WAITL();
            RBAR();
        }
        for (int t = 0; t < 68; t += 4) {
            OF_ITF(t, 0, aA, aB, bP0, bP1, bN0, bN1)
            OF_ITF(t + 2, 1, aB, aA, bN0, bN1, bP0, bP1)
        }
        {  // T=68 tail
            A_LOAD(wpo, 70, aB)
            MFMA8R(aA, 0)
            *(unsigned int*)&sB[1][0][BSLOT2] = bP0;
            *(unsigned int*)&sB[1][1][BSLOT2] = bP1;
            WAITL();
            RBAR();
        }
        MFMA8R(aB, 1)  // T=70
    }

    // =================== prep: acc -> {idx, w01, w23} in LDS ===================
    __syncthreads();
#pragma unroll
    for (int mi = 0; mi < 2; mi++) {
#pragma unroll
        for (int ni = 0; ni < 2; ni++) {
#pragma unroll
            for (int j = 0; j < 4; j++) {
                int oc = w * 32 + mi * 16 + lg * 4 + j;
                if (oc < OFFC) sAcc[oc * 33 + ni * 16 + r16] = acc[mi][ni][j] + off_b[oc];
            }
        }
    }
    __syncthreads();
    for (int i = tid; i < NCHUNK * 32; i += 512) {
        int tt = i >> 5, px = i & 31;
        int dg = (tt * 57) >> 9;
        int tap = tt - dg * 9;
        int ky = tap / 3, kx = tap - ky * 3;
        float dyv = sAcc[(dg * 18 + 2 * tap) * 33 + px];
        float dxv = sAcc[(dg * 18 + 2 * tap + 1) * 33 + px];
        float mr = sAcc[(144 + dg * 9 + tap) * 33 + px];
        int xg = pxh * 32 + px;
        float mv = 1.f / (1.f + __expf(-mr));
        float py = (float)(y + ky - 1) + dyv;
        float pxx = (float)(xg + kx - 1) + dxv;
        float y0f = floorf(py), x0f = floorf(pxx);
        float fy = py - y0f, fx = pxx - x0f;
        int yp0 = min(max((int)y0f + 2, 0), PH - 1);
        int yp1 = min(max((int)y0f + 3, 0), PH - 1);
        int xp0 = min(max((int)x0f + 2, 0), PW - 1);
        int xp1 = min(max((int)x0f + 3, 0), PW - 1);
        prep[tt][px][0] = (unsigned int)(yp0 * PW + xp0) | ((unsigned int)(xp1 - xp0) << 13) |
                          ((unsigned int)(yp1 - yp0) << 14);
        float w00 = (1.f - fy) * (1.f - fx) * mv;
        float w01 = (1.f - fy) * fx * mv;
        float w10 = fy * (1.f - fx) * mv;
        float w11 = fy * fx * mv;
        prep[tt][px][1] = pkbf(w00, w01);
        prep[tt][px][2] = pkbf(w10, w11);
    }
    __syncthreads();

    // =================== phase 2: main GEMM + sampling ===================
#pragma unroll
    for (int mi = 0; mi < 2; mi++)
#pragma unroll
        for (int ni = 0; ni < 2; ni++) acc[mi][ni] = (f32x4)0.f;

#define BSLOT4 (p2px * 32 + ((((ch4 >> 1) ^ ((p2px >> 1) & 3))) << 3) + (ch4 & 1) * 4)
#define DC_G(T, G00, G01, G10, G11)                                       \
    {                                                                     \
        int dg_ = ((T) * 57) >> 9;                                        \
        unsigned int iv_ = prep[T][p2px][0];                              \
        int o00_ = (int)(iv_ & 8191u) << 8;                               \
        int dxe_ = (int)((iv_ >> 13) & 1u) << 8;                          \
        int dye_ = ((iv_ >> 14) & 1u) ? (PW * CC) : 0;                    \
        const unsigned short* p_ = xb + dg_ * 32 + ch4 * 4;               \
        G00 = *(const u32x2*)(p_ + o00_);                                 \
        G01 = *(const u32x2*)(p_ + o00_ + dxe_);                          \
        G10 = *(const u32x2*)(p_ + o00_ + dye_);                          \
        G11 = *(const u32x2*)(p_ + o00_ + dye_ + dxe_);                   \
    }
#define DC_FIN(T, G00, G01, G10, G11, BUF)                                                \
    {                                                                                     \
        unsigned int wa_ = prep[T][p2px][1];                                              \
        unsigned int wb_ = prep[T][p2px][2];                                              \
        float w00 = bflo(wa_), w01 = bfhi(wa_);                                           \
        float w10 = bflo(wb_), w11 = bfhi(wb_);                                           \
        float v0 = w00 * bflo(G00[0]) + w01 * bflo(G01[0]) + w10 * bflo(G10[0]) +         \
                   w11 * bflo(G11[0]);                                                    \
        float v1 = w00 * bfhi(G00[0]) + w01 * bfhi(G01[0]) + w10 * bfhi(G10[0]) +         \
                   w11 * bfhi(G11[0]);                                                    \
        float v2 = w00 * bflo(G00[1]) + w01 * bflo(G01[1]) + w10 * bflo(G10[1]) +         \
                   w11 * bflo(G11[1]);                                                    \
        float v3 = w00 * bfhi(G00[1]) + w01 * bfhi(G01[1]) + w10 * bfhi(G10[1]) +         \
                   w11 * bfhi(G11[1]);                                                    \
        u32x2 pk_;                                                                        \
        pk_[0] = pkbf(v0, v1);                                                            \
        pk_[1] = pkbf(v2, v3);                                                            \
        *(u32x2*)&sB[BUF][kt][BSLOT4] = pk_;                                              \
    }
#define DC_ITF(T, BUF, AC, AN, GP0, GP1, GP2, GP3, GN0, GN1, GN2, GN3)     \
    {                                                                      \
        A_LOAD(wpm, (T) + 2, AN)                                           \
        DC_G((T) + 4 + kt, GN0, GN1, GN2, GN3)                             \
        MFMA8R(AC, BUF)                                                    \
        DC_FIN((T) + 2 + kt, GP0, GP1, GP2, GP3, (BUF) ^ 1)                \
        WAITL();                                                           \
        RBAR();                                                            \
    }

    {
        u32x2 gA0, gA1, gA2, gA3, gB0, gB1, gB2, gB3;
        {  // prologue
            A_LOAD(wpm, 0, aA)
            u32x2 t0, t1, t2, t3;
            DC_G(kt, t0, t1, t2, t3)
            DC_FIN(kt, t0, t1, t2, t3, 0)
            DC_G(2 + kt, gA0, gA1, gA2, gA3)
            WAITL();
            RBAR();
        }
        for (int t = 0; t < 64; t += 4) {
            DC_ITF(t, 0, aA, aB, gA0, gA1, gA2, gA3, gB0, gB1, gB2, gB3)
            DC_ITF(t + 2, 1, aB, aA, gB0, gB1, gB2, gB3, gA0, gA1, gA2, gA3)
        }
        DC_ITF(64, 0, aA, aB, gA0, gA1, gA2, gA3, gB0, gB1, gB2, gB3)
        DC_ITF(66, 1, aB, aA, gB0, gB1, gB2, gB3, gA0, gA1, gA2, gA3)
        {  // T=68: no more gathers to issue
            A_LOAD(wpm, 70, aB)
            MFMA8R(aA, 0)
            DC_FIN(70 + kt, gA0, gA1, gA2, gA3, 1)
            WAITL();
            RBAR();
        }
        MFMA8R(aB, 1)  // T=70
    }

#pragma unroll
    for (int mi = 0; mi < 2; mi++) {
#pragma unroll
        for (int ni = 0; ni < 2; ni++) {
#pragma unroll
            for (int j = 0; j < 4; j++) {
                int oc = w * 32 + mi * 16 + lg * 4 + j;
                int pxo = pxh * 32 + ni * 16 + r16;
                out[(size_t)(b * COUT + oc) * HW + y * WW + pxo] = acc[mi][ni][j] + bias[oc];
            }
        }
    }
}

extern "C" void kernel_launch(void* const* d_in, const int* in_sizes, int n_in,
                              void* d_out, int out_size, void* d_ws, size_t ws_size,
                              hipStream_t stream) {
    const float* x = (const float*)d_in[0];
    const float* extra_feat = (const float*)d_in[1];
    const float* weight = (const float*)d_in[2];
    const float* bias = (const float*)d_in[3];
    const float* off_w = (const float*)d_in[4];
    const float* off_b = (const float*)d_in[5];
    float* out = (float*)d_out;

    unsigned short* wpm = (unsigned short*)d_ws;            // 1.18 MB
    unsigned short* wpo = wpm + (size_t)KTOT * COUT;        // 1.18 MB
    unsigned short* xT = wpo + (size_t)KTOT * COUT;         // 9.05 MB
    unsigned short* eT = xT + (size_t)BB * PH * PW * CC;    // 9.05 MB

    pack_w_main<<<(KTOT * COUT) / 256, 256, 0, stream>>>(weight, wpm);
    pack_w_off<<<(KTOT * COUT) / 256, 256, 0, stream>>>(off_w, wpo);
    pad_tr2<<<dim3(BB * PH, 2), 256, 0, stream>>>(x, extra_feat, xT, eT);

    fused_dcn<<<dim3(BB * HH, 2), 512, 0, stream>>>(eT, xT, wpo, wpm, off_b, bias, out);
}